// Round 1
// baseline (495.160 us; speedup 1.0000x reference)
//
#include <hip/hip_runtime.h>

#define NP   8192
#define BB   4
#define DIN  32
#define M0   32
#define M1   32
#define M2   64
#define KK   16
#define CAP  64

__device__ __forceinline__ float lrelu(float x) { return fmaxf(x, 0.1f * x); }

__device__ __forceinline__ float dist2(float4 p, float qx, float qy, float qz, float qs) {
    return qs + p.w - 2.0f * (qx * p.x + qy * p.y + qz * p.z);
}

// ---------------------------------------------------------------------------
// Kernel 1: pack (x,y,z,|x|^2) per point, and pre-transform features with
// W0[:,3:]  -> feat[b][n][32] (gather-friendly layout).
// ---------------------------------------------------------------------------
__global__ __launch_bounds__(256) void prep_kernel(
    const float* __restrict__ xyz, const float* __restrict__ points,
    const float* __restrict__ W0, float4* __restrict__ pts4, float* __restrict__ feat)
{
    int t = blockIdx.x * 256 + threadIdx.x;      // 0 .. B*N-1
    int b = t >> 13;
    int n = t & (NP - 1);
    const float* xb = xyz + (size_t)b * 3 * NP;
    float x = xb[n], y = xb[NP + n], z = xb[2 * NP + n];
    pts4[t] = make_float4(x, y, z, x * x + y * y + z * z);

    const float* pb = points + (size_t)b * DIN * NP + n;
    float p[DIN];
#pragma unroll
    for (int c = 0; c < DIN; ++c) p[c] = pb[c * NP];

    float4* fo = (float4*)(feat + (size_t)t * M0);
#pragma unroll
    for (int og = 0; og < M0 / 4; ++og) {
        float4 v;
        float* vv = (float*)&v;
#pragma unroll
        for (int r = 0; r < 4; ++r) {
            int o = og * 4 + r;
            float acc = 0.f;
#pragma unroll
            for (int c = 0; c < DIN; ++c) acc = fmaf(W0[o * 35 + 3 + c], p[c], acc);
            vv[r] = acc;
        }
        fo[og] = v;
    }
}

// ---------------------------------------------------------------------------
// Kernel 2: exact 16-NN via two-pass threshold selection.
// Block = 4 waves, 64 queries (lane = query). Wave w scans points
// [w*2048,(w+1)*2048) -- the scan index is wave-uniform => scalar loads.
// Pass 1: 32 per-class minima per (query, wave) -> T = 16th smallest of the
//         128 minima (provable upper bound on d_16, typically very tight).
// Pass 2: append all d<=T to an LDS candidate buffer (rare path).
// Final : per-query serial exact top-16 with (d, idx) tie-break.
// ---------------------------------------------------------------------------
__global__ __launch_bounds__(256) void knn_kernel(const float4* __restrict__ pts4,
                                                  int* __restrict__ idxout)
{
    __shared__ float s_pool[32 * 64 * 4];   // 32 KB: pass-1 minima, reused as candidates
    __shared__ float sT[64];
    __shared__ int scnt[64];

    const int tid  = threadIdx.x;
    const int w    = __builtin_amdgcn_readfirstlane(tid >> 6);
    const int lane = tid & 63;
    const int blk  = blockIdx.x;           // 512 blocks
    const int b    = blk >> 7;             // 128 blocks per batch
    const int n0   = (blk & 127) << 6;
    const float4* P = pts4 + b * NP;
    const int q = n0 + lane;
    float4 me = P[q];
    const float qx = me.x, qy = me.y, qz = me.z, qs = me.w;

    // ---- pass 1: class minima (no divergence, statically indexed) ----
    float m[32];
#pragma unroll
    for (int c = 0; c < 32; ++c) m[c] = 1e30f;
    const int base = w * 2048;
    for (int i = 0; i < 2048; i += 32) {
#pragma unroll
        for (int c = 0; c < 32; ++c) {
            float4 p = P[base + i + c];          // wave-uniform -> s_load
            float d = dist2(p, qx, qy, qz, qs);
            m[c] = fminf(m[c], d);
        }
    }
#pragma unroll
    for (int c = 0; c < 32; ++c) s_pool[(w * 32 + c) * 64 + lane] = m[c];
    __syncthreads();

    // ---- threshold: 16th smallest of the 128 minima (wave 0 only) ----
    if (tid < 64) {
        float t16[16];
#pragma unroll
        for (int i = 0; i < 16; ++i) t16[i] = 1e30f;
        for (int v = 0; v < 128; ++v) {
            float d = s_pool[v * 64 + tid];
            if (d < t16[15]) {
                t16[15] = d;
#pragma unroll
                for (int i = 15; i > 0; --i) {
                    float a = t16[i - 1], c = t16[i];
                    t16[i - 1] = fminf(a, c);
                    t16[i]     = fmaxf(a, c);
                }
            }
        }
        sT[tid]   = t16[15];
        scnt[tid] = 0;
    }
    __syncthreads();

    // ---- pass 2: gather candidates with d <= T ----
    float* cand_d = s_pool;                     // [pos*64 + q]
    int*   cand_i = (int*)(s_pool + CAP * 64);  // [pos*64 + q]
    const float T = sT[lane];
    for (int i = 0; i < 2048; i += 8) {
#pragma unroll
        for (int c = 0; c < 8; ++c) {
            int j = base + i + c;
            float4 p = P[j];
            float d = dist2(p, qx, qy, qz, qs);
            if (d <= T) {
                int pos = atomicAdd(&scnt[lane], 1);
                if (pos < CAP) { cand_d[pos * 64 + lane] = d; cand_i[pos * 64 + lane] = j; }
            }
        }
    }
    __syncthreads();

    // ---- exact selection among candidates (one thread per query) ----
    if (tid < 64) {
        int cnt = scnt[tid];
        int* outp = idxout + ((b * NP + n0 + tid) << 4);
        float bd[16]; int bi[16];
#pragma unroll
        for (int i = 0; i < 16; ++i) { bd[i] = 3e38f; bi[i] = 0; }
        if (cnt <= CAP) {
            for (int pos = 0; pos < cnt; ++pos) {
                float d = cand_d[pos * 64 + tid];
                int   j = cand_i[pos * 64 + tid];
                if ((d < bd[15]) || (d == bd[15] && j < bi[15])) {
                    bd[15] = d; bi[15] = j;
#pragma unroll
                    for (int i = 15; i > 0; --i) {
                        bool sw = (bd[i] < bd[i - 1]) || (bd[i] == bd[i - 1] && bi[i] < bi[i - 1]);
                        float td = bd[i - 1]; int tj = bi[i - 1];
                        bd[i - 1] = sw ? bd[i] : td;  bi[i - 1] = sw ? bi[i] : tj;
                        bd[i]     = sw ? td : bd[i];  bi[i]     = sw ? tj : bi[i];
                    }
                }
            }
        } else {
            // overflow fallback (essentially never taken): exact serial scan
            const int qq = n0 + tid;
            float4 meq = P[qq];
            for (int j = 0; j < NP; ++j) {
                float4 p = P[j];
                float d = dist2(p, meq.x, meq.y, meq.z, meq.w);
                if ((d < bd[15]) || (d == bd[15] && j < bi[15])) {
                    bd[15] = d; bi[15] = j;
#pragma unroll
                    for (int i = 15; i > 0; --i) {
                        bool sw = (bd[i] < bd[i - 1]) || (bd[i] == bd[i - 1] && bi[i] < bi[i - 1]);
                        float td = bd[i - 1]; int tj = bi[i - 1];
                        bd[i - 1] = sw ? bd[i] : td;  bi[i - 1] = sw ? bi[i] : tj;
                        bd[i]     = sw ? td : bd[i];  bi[i]     = sw ? tj : bi[i];
                    }
                }
            }
        }
#pragma unroll
        for (int i = 0; i < 16; ++i) outp[i] = bi[i];
    }
}

// ---------------------------------------------------------------------------
// Kernel 3: gather + conv0 + conv1 + conv2 (leaky relu) + max over K.
// One thread per (n, k) column; weights via wave-uniform scalar loads;
// fully-unrolled register-resident chain; k-max via shfl_xor width 16.
// ---------------------------------------------------------------------------
__global__ __launch_bounds__(256) void conv_kernel(
    const float4* __restrict__ pts4, const float* __restrict__ feat,
    const int* __restrict__ idx,
    const float* __restrict__ W0, const float* __restrict__ W1, const float* __restrict__ W2,
    float* __restrict__ out)
{
    __shared__ float so[M2][17];
    const int tid = threadIdx.x;
    const int k   = tid & 15;
    const int nl  = tid >> 4;              // 0..15
    const int blk = blockIdx.x;            // 2048 blocks
    const int b   = blk >> 9;              // 512 blocks per batch
    const int n0  = (blk & 511) << 4;
    const int n   = n0 + nl;
    const int bn  = b * NP + n;
    const int j   = idx[(bn << 4) + k];

    const float4 pj = pts4[b * NP + j];
    const float4 pc = pts4[bn];
    const float rx = pj.x - pc.x, ry = pj.y - pc.y, rz = pj.z - pc.z;

    const float4* fj = (const float4*)(feat + ((size_t)(b * NP + j) << 5));

    float x0[M0];
#pragma unroll
    for (int g = 0; g < M0 / 4; ++g) {
        float4 f = fj[g];
        const float* fv = (const float*)&f;
#pragma unroll
        for (int r = 0; r < 4; ++r) {
            int o = g * 4 + r;
            float t = fmaf(W0[o * 35], rx, fmaf(W0[o * 35 + 1], ry, W0[o * 35 + 2] * rz));
            x0[o] = lrelu(t + fv[r]);
        }
    }

    float x1[M1];
#pragma unroll
    for (int o = 0; o < M1; ++o) {
        float acc = 0.f;
#pragma unroll
        for (int c = 0; c < M0; ++c) acc = fmaf(W1[o * 32 + c], x0[c], acc);
        x1[o] = lrelu(acc);
    }

    float x2[M2];
#pragma unroll
    for (int o = 0; o < M2; ++o) {
        float acc = 0.f;
#pragma unroll
        for (int c = 0; c < M1; ++c) acc = fmaf(W2[o * 32 + c], x1[c], acc);
        x2[o] = lrelu(acc);
    }

    // max over the 16 k-lanes (aligned 16-lane groups)
#pragma unroll
    for (int o = 0; o < M2; ++o) {
        float v = x2[o];
        v = fmaxf(v, __shfl_xor(v, 1, 16));
        v = fmaxf(v, __shfl_xor(v, 2, 16));
        v = fmaxf(v, __shfl_xor(v, 4, 16));
        v = fmaxf(v, __shfl_xor(v, 8, 16));
        x2[o] = v;
    }

    // stage to LDS (pad 17 to break bank conflicts), then coalesced stores
#pragma unroll
    for (int r = 0; r < 4; ++r) so[k * 4 + r][nl] = x2[k * 4 + r];
    __syncthreads();
    {
        int o = tid >> 2;
        int s = tid & 3;
        float4 v = make_float4(so[o][4 * s], so[o][4 * s + 1], so[o][4 * s + 2], so[o][4 * s + 3]);
        float* op = out + ((size_t)(b * M2 + o)) * NP + n0 + 4 * s;
        *(float4*)op = v;
    }
}

// ---------------------------------------------------------------------------
extern "C" void kernel_launch(void* const* d_in, const int* in_sizes, int n_in,
                              void* d_out, int out_size, void* d_ws, size_t ws_size,
                              hipStream_t stream)
{
    const float* xyz    = (const float*)d_in[0];
    const float* points = (const float*)d_in[1];
    const float* W0     = (const float*)d_in[2];
    const float* W1     = (const float*)d_in[3];
    const float* W2     = (const float*)d_in[4];
    float* out = (float*)d_out;

    char* ws = (char*)d_ws;
    float4* pts4 = (float4*)ws;                                  // 512 KB
    float*  feat = (float*)(ws + 524288);                        // 4 MB
    int*    idx  = (int*)(ws + 524288 + 4194304);                // 2 MB

    prep_kernel<<<BB * NP / 256, 256, 0, stream>>>(xyz, points, W0, pts4, feat);
    knn_kernel <<<BB * NP / 64,  256, 0, stream>>>(pts4, idx);
    conv_kernel<<<BB * NP / 16,  256, 0, stream>>>(pts4, feat, idx, W0, W1, W2, out);
}

// Round 2
// 314.186 us; speedup vs baseline: 1.5760x; 1.5760x over previous
//
#include <hip/hip_runtime.h>

#define NP   8192
#define BB   4
#define DIN  32
#define M0   32
#define M1   32
#define M2   64
#define KK   16
#define CAP  64
#define WV   8      // waves per knn block

__device__ __forceinline__ float lrelu(float x) { return fmaxf(x, 0.1f * x); }

__device__ __forceinline__ float dist2(float4 p, float qx, float qy, float qz, float qs) {
    return fmaf(-2.0f, fmaf(qx, p.x, fmaf(qy, p.y, qz * p.z)), qs + p.w);
}

// ---------------------------------------------------------------------------
// Kernel 1: pack (x,y,z,|x|^2) per point, and pre-transform features with
// W0[:,3:]  -> feat[b][n][32] (gather-friendly layout).
// ---------------------------------------------------------------------------
__global__ __launch_bounds__(256) void prep_kernel(
    const float* __restrict__ xyz, const float* __restrict__ points,
    const float* __restrict__ W0, float4* __restrict__ pts4, float* __restrict__ feat)
{
    int t = blockIdx.x * 256 + threadIdx.x;      // 0 .. B*N-1
    int b = t >> 13;
    int n = t & (NP - 1);
    const float* xb = xyz + (size_t)b * 3 * NP;
    float x = xb[n], y = xb[NP + n], z = xb[2 * NP + n];
    pts4[t] = make_float4(x, y, z, x * x + y * y + z * z);

    const float* pb = points + (size_t)b * DIN * NP + n;
    float p[DIN];
#pragma unroll
    for (int c = 0; c < DIN; ++c) p[c] = pb[c * NP];

    float4* fo = (float4*)(feat + (size_t)t * M0);
#pragma unroll
    for (int og = 0; og < M0 / 4; ++og) {
        float4 v;
        float* vv = (float*)&v;
#pragma unroll
        for (int r = 0; r < 4; ++r) {
            int o = og * 4 + r;
            float acc = 0.f;
#pragma unroll
            for (int c = 0; c < DIN; ++c) acc = fmaf(W0[o * 35 + 3 + c], p[c], acc);
            vv[r] = acc;
        }
        fo[og] = v;
    }
}

// ---------------------------------------------------------------------------
// Kernel 2: exact 16-NN, two-pass threshold selection, 8 waves/block.
// Wave w scans points [w*1024,(w+1)*1024) (wave-uniform index => s_load).
// Pass 1: per-wave 32 class minima (class = j mod 32) -> parallel fmin-reduce
//         across waves -> 32 GLOBAL class minima per query.
// T = 16th smallest of the 32 global class minima: each class minimum is the
//     distance of a distinct point, so >=16 points have d <= T  =>  d16 <= T.
// Pass 2: append all d<=T to LDS candidate buffer (E[cand] ~ 22, CAP=64).
// Final : per-query serial exact top-16 with (d, idx) tie-break; overflow
//         falls back to exact full scan (never expected).
// ---------------------------------------------------------------------------
__global__ __launch_bounds__(512) void knn_kernel(const float4* __restrict__ pts4,
                                                  int* __restrict__ idxout)
{
    __shared__ float s_pool[WV * 32 * 64];   // 64 KB: minima, then candidates
    __shared__ float sT[64];
    __shared__ int scnt[64];

    const int tid  = threadIdx.x;
    const int w    = __builtin_amdgcn_readfirstlane(tid >> 6);
    const int lane = tid & 63;
    const int blk  = blockIdx.x;           // 512 blocks
    const int b    = blk >> 7;             // 128 blocks per batch
    const int n0   = (blk & 127) << 6;
    const float4* P = pts4 + b * NP;
    const int q = n0 + lane;
    float4 me = P[q];
    const float qx = me.x, qy = me.y, qz = me.z, qs = me.w;

    // ---- pass 1: per-wave class minima (no divergence, static indexing) ----
    float m[32];
#pragma unroll
    for (int c = 0; c < 32; ++c) m[c] = 1e30f;
    const int base = w * 1024;
    for (int i = 0; i < 1024; i += 32) {
#pragma unroll
        for (int c = 0; c < 32; ++c) {
            float4 p = P[base + i + c];          // wave-uniform -> s_load
            float d = dist2(p, qx, qy, qz, qs);
            m[c] = fminf(m[c], d);
        }
    }
#pragma unroll
    for (int c = 0; c < 32; ++c) s_pool[(w * 32 + c) * 64 + lane] = m[c];
    __syncthreads();

    // ---- fmin-reduce across the 8 waves: 2048 (c,q) pairs, 512 threads ----
#pragma unroll
    for (int r = 0; r < 4; ++r) {
        int p = tid + r * 512;
        float v = s_pool[p];
#pragma unroll
        for (int ww = 1; ww < WV; ++ww) v = fminf(v, s_pool[ww * 2048 + p]);
        s_pool[p] = v;                    // global class minima in s_pool[0..2047]
    }
    __syncthreads();

    // ---- threshold: 16th smallest of the 32 global class minima ----
    if (tid < 64) {
        float t16[16];
#pragma unroll
        for (int i = 0; i < 16; ++i) t16[i] = 1e30f;
#pragma unroll
        for (int c = 0; c < 32; ++c) {
            float d = s_pool[c * 64 + tid];
            if (d < t16[15]) {
                t16[15] = d;
#pragma unroll
                for (int i = 15; i > 0; --i) {
                    float a = t16[i - 1], cc = t16[i];
                    t16[i - 1] = fminf(a, cc);
                    t16[i]     = fmaxf(a, cc);
                }
            }
        }
        sT[tid]   = t16[15];
        scnt[tid] = 0;
    }
    __syncthreads();

    // ---- pass 2: gather candidates with d <= T ----
    float* cand_d = s_pool;                     // [pos*64 + q]
    int*   cand_i = (int*)(s_pool + CAP * 64);  // [pos*64 + q]
    const float T = sT[lane];
    for (int i = 0; i < 1024; i += 8) {
#pragma unroll
        for (int c = 0; c < 8; ++c) {
            int j = base + i + c;
            float4 p = P[j];
            float d = dist2(p, qx, qy, qz, qs);
            if (d <= T) {
                int pos = atomicAdd(&scnt[lane], 1);
                if (pos < CAP) { cand_d[pos * 64 + lane] = d; cand_i[pos * 64 + lane] = j; }
            }
        }
    }
    __syncthreads();

    // ---- exact selection among candidates (one thread per query) ----
    if (tid < 64) {
        int cnt = scnt[tid];
        int* outp = idxout + ((b * NP + n0 + tid) << 4);
        float bd[16]; int bi[16];
#pragma unroll
        for (int i = 0; i < 16; ++i) { bd[i] = 3e38f; bi[i] = 0; }
        if (cnt <= CAP) {
            for (int pos = 0; pos < cnt; ++pos) {
                float d = cand_d[pos * 64 + tid];
                int   j = cand_i[pos * 64 + tid];
                if ((d < bd[15]) || (d == bd[15] && j < bi[15])) {
                    bd[15] = d; bi[15] = j;
#pragma unroll
                    for (int i = 15; i > 0; --i) {
                        bool sw = (bd[i] < bd[i - 1]) || (bd[i] == bd[i - 1] && bi[i] < bi[i - 1]);
                        float td = bd[i - 1]; int tj = bi[i - 1];
                        bd[i - 1] = sw ? bd[i] : td;  bi[i - 1] = sw ? bi[i] : tj;
                        bd[i]     = sw ? td : bd[i];  bi[i]     = sw ? tj : bi[i];
                    }
                }
            }
        } else {
            // overflow fallback (essentially never taken): exact serial scan
            const int qq = n0 + tid;
            float4 meq = P[qq];
            for (int j = 0; j < NP; ++j) {
                float4 p = P[j];
                float d = dist2(p, meq.x, meq.y, meq.z, meq.w);
                if ((d < bd[15]) || (d == bd[15] && j < bi[15])) {
                    bd[15] = d; bi[15] = j;
#pragma unroll
                    for (int i = 15; i > 0; --i) {
                        bool sw = (bd[i] < bd[i - 1]) || (bd[i] == bd[i - 1] && bi[i] < bi[i - 1]);
                        float td = bd[i - 1]; int tj = bi[i - 1];
                        bd[i - 1] = sw ? bd[i] : td;  bi[i - 1] = sw ? bi[i] : tj;
                        bd[i]     = sw ? td : bd[i];  bi[i]     = sw ? tj : bi[i];
                    }
                }
            }
        }
#pragma unroll
        for (int i = 0; i < 16; ++i) outp[i] = bi[i];
    }
}

// ---------------------------------------------------------------------------
// Kernel 3: gather + conv0 + conv1 + conv2 (leaky relu) + max over K.
// One thread per (n, k) column. x2 is never materialized as an array:
// each output o is computed into one register, butterfly-maxed over the 16
// k-lanes, and written to LDS by lane k == o%16. Keeps VGPR ~100.
// ---------------------------------------------------------------------------
__global__ __launch_bounds__(256) void conv_kernel(
    const float4* __restrict__ pts4, const float* __restrict__ feat,
    const int* __restrict__ idx,
    const float* __restrict__ W0, const float* __restrict__ W1, const float* __restrict__ W2,
    float* __restrict__ out)
{
    __shared__ float so[M2][17];
    const int tid = threadIdx.x;
    const int k   = tid & 15;
    const int nl  = tid >> 4;              // 0..15
    const int blk = blockIdx.x;            // 2048 blocks
    const int b   = blk >> 9;              // 512 blocks per batch
    const int n0  = (blk & 511) << 4;
    const int n   = n0 + nl;
    const int bn  = b * NP + n;
    const int j   = idx[(bn << 4) + k];

    const float4 pj = pts4[b * NP + j];
    const float4 pc = pts4[bn];
    const float rx = pj.x - pc.x, ry = pj.y - pc.y, rz = pj.z - pc.z;

    const float4* fj = (const float4*)(feat + ((size_t)(b * NP + j) << 5));

    float x0[M0];
#pragma unroll
    for (int g = 0; g < M0 / 4; ++g) {
        float4 f = fj[g];
        const float* fv = (const float*)&f;
#pragma unroll
        for (int r = 0; r < 4; ++r) {
            int o = g * 4 + r;
            float t = fmaf(W0[o * 35], rx, fmaf(W0[o * 35 + 1], ry, W0[o * 35 + 2] * rz));
            x0[o] = lrelu(t + fv[r]);
        }
    }

    float x1[M1];
#pragma unroll
    for (int o = 0; o < M1; ++o) {
        float acc = 0.f;
#pragma unroll
        for (int c = 0; c < M0; ++c) acc = fmaf(W1[o * 32 + c], x0[c], acc);
        x1[o] = lrelu(acc);
    }

    // conv2: one output at a time -> butterfly max over 16 k-lanes -> LDS
#pragma unroll
    for (int o = 0; o < M2; ++o) {
        float acc = 0.f;
#pragma unroll
        for (int c = 0; c < M1; ++c) acc = fmaf(W2[o * 32 + c], x1[c], acc);
        float v = lrelu(acc);
        v = fmaxf(v, __shfl_xor(v, 1, 16));
        v = fmaxf(v, __shfl_xor(v, 2, 16));
        v = fmaxf(v, __shfl_xor(v, 4, 16));
        v = fmaxf(v, __shfl_xor(v, 8, 16));
        if (k == (o & 15)) so[o][nl] = v;
    }
    __syncthreads();
    {
        int o = tid >> 2;
        int s = tid & 3;
        float4 v = make_float4(so[o][4 * s], so[o][4 * s + 1], so[o][4 * s + 2], so[o][4 * s + 3]);
        float* op = out + ((size_t)(b * M2 + o)) * NP + n0 + 4 * s;
        *(float4*)op = v;
    }
}

// ---------------------------------------------------------------------------
extern "C" void kernel_launch(void* const* d_in, const int* in_sizes, int n_in,
                              void* d_out, int out_size, void* d_ws, size_t ws_size,
                              hipStream_t stream)
{
    const float* xyz    = (const float*)d_in[0];
    const float* points = (const float*)d_in[1];
    const float* W0     = (const float*)d_in[2];
    const float* W1     = (const float*)d_in[3];
    const float* W2     = (const float*)d_in[4];
    float* out = (float*)d_out;

    char* ws = (char*)d_ws;
    float4* pts4 = (float4*)ws;                                  // 512 KB
    float*  feat = (float*)(ws + 524288);                        // 4 MB
    int*    idx  = (int*)(ws + 524288 + 4194304);                // 2 MB

    prep_kernel<<<BB * NP / 256, 256, 0, stream>>>(xyz, points, W0, pts4, feat);
    knn_kernel <<<BB * NP / 64,  512, 0, stream>>>(pts4, idx);
    conv_kernel<<<BB * NP / 16,  256, 0, stream>>>(pts4, feat, idx, W0, W1, W2, out);
}

// Round 3
// 288.545 us; speedup vs baseline: 1.7161x; 1.0889x over previous
//
#include <hip/hip_runtime.h>

#define NP   8192
#define BB   4
#define DIN  32
#define M0   32
#define M1   32
#define M2   64
#define KK   16
#define CAP  80
#define KWV  16     // waves per knn block
#define SEG  (NP / KWV)   // 512 points per wave

typedef float v2f __attribute__((ext_vector_type(2)));

__device__ __forceinline__ float lrelu(float x) { return fmaxf(x, 0.1f * x); }
__device__ __forceinline__ v2f lrelu2(v2f x) { return __builtin_elementwise_max(x, 0.1f * x); }
__device__ __forceinline__ unsigned umin_(unsigned a, unsigned b) { return a < b ? a : b; }
__device__ __forceinline__ unsigned umax_(unsigned a, unsigned b) { return a > b ? a : b; }

// monotonic float->uint key (total order, works for negatives)
__device__ __forceinline__ unsigned fkey(float f) {
    unsigned b = __float_as_uint(f);
    return (b & 0x80000000u) ? ~b : (b | 0x80000000u);
}
__device__ __forceinline__ float funkey(unsigned k) {
    unsigned b = (k & 0x80000000u) ? (k & 0x7fffffffu) : ~k;
    return __uint_as_float(b);
}

// ---------------------------------------------------------------------------
// Kernel 1: pack (x,y,z,|x|^2); feat = W0[:,3:] @ points  ([B,N,32] layout).
// 4 threads per point (sub = g>>15 is wave-uniform => W0 stays s_load).
// ---------------------------------------------------------------------------
__global__ __launch_bounds__(256) void prep_kernel(
    const float* __restrict__ xyz, const float* __restrict__ points,
    const float* __restrict__ W0, float4* __restrict__ pts4, float* __restrict__ feat)
{
    int g = blockIdx.x * 256 + threadIdx.x;      // 0 .. 4*B*N-1
    int sub = g >> 15;                           // 0..3 (wave-uniform)
    int t = g & (BB * NP - 1);                   // point id
    int b = t >> 13;
    int n = t & (NP - 1);

    if (sub == 0) {
        const float* xb = xyz + (size_t)b * 3 * NP;
        float x = xb[n], y = xb[NP + n], z = xb[2 * NP + n];
        pts4[t] = make_float4(x, y, z, x * x + y * y + z * z);
    }

    const float* pb = points + (size_t)b * DIN * NP + n;
    float p[DIN];
#pragma unroll
    for (int c = 0; c < DIN; ++c) p[c] = pb[c * NP];

    float4* fo = (float4*)(feat + (size_t)t * M0);
#pragma unroll
    for (int og = 0; og < 2; ++og) {
        float4 v;
        float* vv = (float*)&v;
#pragma unroll
        for (int r = 0; r < 4; ++r) {
            int o = sub * 8 + og * 4 + r;
            float acc = 0.f;
#pragma unroll
            for (int c = 0; c < DIN; ++c) acc = fmaf(W0[o * 35 + 3 + c], p[c], acc);
            vv[r] = acc;
        }
        fo[sub * 2 + og] = v;
    }
}

// ---------------------------------------------------------------------------
// Kernel 2: exact 16-NN. 16 waves/block, 64 queries/block (lane = query).
// Metric: t = |p|^2 - 2 q.p  (= d - |q|^2, order-preserving per query).
// Pass 1: per-wave 32 class minima over its 512-pt segment -> ds_min_u32
//         merge into 32 GLOBAL class minima (8 KB LDS, key space).
// T = 16th smallest of 32 global class minima (>=16 distinct points <= T).
// Pass 2: append t<=T candidates; exact (t,idx)-lex top-16 per query.
// ---------------------------------------------------------------------------
__global__ __launch_bounds__(1024, 8) void knn_kernel(const float4* __restrict__ pts4,
                                                      int* __restrict__ idxout)
{
    __shared__ unsigned skey[32 * 64];     // 8 KB global class-min keys
    __shared__ float cand_t[CAP * 64];     // 20 KB
    __shared__ int   cand_i[CAP * 64];     // 20 KB
    __shared__ float sT[64];
    __shared__ int   scnt[64];

    const int tid  = threadIdx.x;
    const int w    = __builtin_amdgcn_readfirstlane(tid >> 6);
    const int lane = tid & 63;
    const int blk  = blockIdx.x;           // 512 blocks
    const int b    = blk >> 7;
    const int n0   = (blk & 127) << 6;
    const float4* P = pts4 + b * NP;
    const int q = n0 + lane;
    float4 me = P[q];
    const float qx = me.x, qy = me.y, qz = me.z;

    skey[tid] = 0xFFFFFFFFu;
    skey[tid + 1024] = 0xFFFFFFFFu;
    if (tid < 64) scnt[tid] = 0;
    __syncthreads();

    // ---- pass 1: per-wave class minima (class = j mod 32) ----
    float m[32];
#pragma unroll
    for (int c = 0; c < 32; ++c) m[c] = 1e30f;
    const int base = w * SEG;
    for (int i = 0; i < SEG; i += 32) {
#pragma unroll
        for (int c = 0; c < 32; ++c) {
            float4 p = P[base + i + c];          // wave-uniform -> s_load
            float dot = fmaf(qx, p.x, fmaf(qy, p.y, qz * p.z));
            m[c] = fminf(m[c], fmaf(-2.0f, dot, p.w));
        }
    }
#pragma unroll
    for (int c = 0; c < 32; ++c) atomicMin(&skey[c * 64 + lane], fkey(m[c]));
    __syncthreads();

    // ---- threshold: 16th smallest of the 32 global class minima ----
    if (tid < 64) {
        unsigned t16[16];
#pragma unroll
        for (int i = 0; i < 16; ++i) t16[i] = 0xFFFFFFFFu;
#pragma unroll
        for (int c = 0; c < 32; ++c) {
            unsigned d = skey[c * 64 + tid];
            if (d < t16[15]) {
                t16[15] = d;
#pragma unroll
                for (int i = 15; i > 0; --i) {
                    unsigned a = t16[i - 1], cc = t16[i];
                    t16[i - 1] = umin_(a, cc);
                    t16[i]     = umax_(a, cc);
                }
            }
        }
        sT[tid] = funkey(t16[15]);
    }
    __syncthreads();

    // ---- pass 2: gather candidates with t <= T ----
    const float T = sT[lane];
    for (int i = 0; i < SEG; i += 8) {
#pragma unroll
        for (int c = 0; c < 8; ++c) {
            int j = base + i + c;
            float4 p = P[j];
            float dot = fmaf(qx, p.x, fmaf(qy, p.y, qz * p.z));
            float t = fmaf(-2.0f, dot, p.w);
            if (t <= T) {
                int pos = atomicAdd(&scnt[lane], 1);
                if (pos < CAP) { cand_t[pos * 64 + lane] = t; cand_i[pos * 64 + lane] = j; }
            }
        }
    }
    __syncthreads();

    // ---- exact selection among candidates (one thread per query) ----
    if (tid < 64) {
        int cnt = scnt[tid];
        int* outp = idxout + ((b * NP + n0 + tid) << 4);
        float bd[16]; int bi[16];
#pragma unroll
        for (int i = 0; i < 16; ++i) { bd[i] = 3e38f; bi[i] = 0; }
        if (cnt <= CAP) {
            for (int pos = 0; pos < cnt; ++pos) {
                float d = cand_t[pos * 64 + tid];
                int   j = cand_i[pos * 64 + tid];
                if ((d < bd[15]) || (d == bd[15] && j < bi[15])) {
                    bd[15] = d; bi[15] = j;
#pragma unroll
                    for (int i = 15; i > 0; --i) {
                        bool sw = (bd[i] < bd[i - 1]) || (bd[i] == bd[i - 1] && bi[i] < bi[i - 1]);
                        float td = bd[i - 1]; int tj = bi[i - 1];
                        bd[i - 1] = sw ? bd[i] : td;  bi[i - 1] = sw ? bi[i] : tj;
                        bd[i]     = sw ? td : bd[i];  bi[i]     = sw ? tj : bi[i];
                    }
                }
            }
        } else {
            // overflow fallback (exact, never expected)
            float4 meq = P[n0 + tid];
            for (int j = 0; j < NP; ++j) {
                float4 p = P[j];
                float dot = fmaf(meq.x, p.x, fmaf(meq.y, p.y, meq.z * p.z));
                float d = fmaf(-2.0f, dot, p.w);
                if ((d < bd[15]) || (d == bd[15] && j < bi[15])) {
                    bd[15] = d; bi[15] = j;
#pragma unroll
                    for (int i = 15; i > 0; --i) {
                        bool sw = (bd[i] < bd[i - 1]) || (bd[i] == bd[i - 1] && bi[i] < bi[i - 1]);
                        float td = bd[i - 1]; int tj = bi[i - 1];
                        bd[i - 1] = sw ? bd[i] : td;  bi[i - 1] = sw ? bi[i] : tj;
                        bd[i]     = sw ? td : bd[i];  bi[i]     = sw ? tj : bi[i];
                    }
                }
            }
        }
#pragma unroll
        for (int i = 0; i < 16; ++i) outp[i] = bi[i];
    }
}

// ---------------------------------------------------------------------------
// Kernel 3: gather + conv0/1/2 + max over K. One thread per (n, k-pair):
// handles neighbors k and k+8 as float2 -> v_pk_fma_f32 dual fp32.
// Max: in-register pair max + 3x shfl_xor (width 8).
// ---------------------------------------------------------------------------
__global__ __launch_bounds__(256) void conv_kernel(
    const float4* __restrict__ pts4, const float* __restrict__ feat,
    const int* __restrict__ idx,
    const float* __restrict__ W0, const float* __restrict__ W1, const float* __restrict__ W2,
    float* __restrict__ out)
{
    __shared__ float so[M2][33];
    const int tid = threadIdx.x;
    const int k   = tid & 7;
    const int nl  = tid >> 3;              // 0..31
    const int blk = blockIdx.x;            // 1024 blocks
    const int b   = blk >> 8;              // 256 blocks per batch
    const int n0  = (blk & 255) << 5;
    const int n   = n0 + nl;
    const int bn  = b * NP + n;
    const int j0  = idx[(bn << 4) + k];
    const int j1  = idx[(bn << 4) + k + 8];

    const float4 pc = pts4[bn];
    const float4 p0 = pts4[b * NP + j0];
    const float4 p1 = pts4[b * NP + j1];
    const v2f rx = {p0.x - pc.x, p1.x - pc.x};
    const v2f ry = {p0.y - pc.y, p1.y - pc.y};
    const v2f rz = {p0.z - pc.z, p1.z - pc.z};

    const float4* f0 = (const float4*)(feat + ((size_t)(b * NP + j0) << 5));
    const float4* f1 = (const float4*)(feat + ((size_t)(b * NP + j1) << 5));

    v2f x0[M0];
#pragma unroll
    for (int g = 0; g < M0 / 4; ++g) {
        float4 a = f0[g], c4 = f1[g];
        const float* av = (const float*)&a;
        const float* cv = (const float*)&c4;
#pragma unroll
        for (int r = 0; r < 4; ++r) {
            int o = g * 4 + r;
            float w0 = W0[o * 35], w1 = W0[o * 35 + 1], w2 = W0[o * 35 + 2];
            v2f f = {av[r], cv[r]};
            v2f t = __builtin_elementwise_fma((v2f){w0, w0}, rx,
                    __builtin_elementwise_fma((v2f){w1, w1}, ry,
                    __builtin_elementwise_fma((v2f){w2, w2}, rz, f)));
            x0[o] = lrelu2(t);
        }
    }

    v2f x1[M1];
#pragma unroll
    for (int o = 0; o < M1; ++o) {
        v2f acc = {0.f, 0.f};
#pragma unroll
        for (int c = 0; c < M0; ++c) {
            float w = W1[o * 32 + c];
            acc = __builtin_elementwise_fma((v2f){w, w}, x0[c], acc);
        }
        x1[o] = lrelu2(acc);
    }

#pragma unroll
    for (int o = 0; o < M2; ++o) {
        v2f acc = {0.f, 0.f};
#pragma unroll
        for (int c = 0; c < M1; ++c) {
            float w = W2[o * 32 + c];
            acc = __builtin_elementwise_fma((v2f){w, w}, x1[c], acc);
        }
        acc = lrelu2(acc);
        float v = fmaxf(acc.x, acc.y);
        v = fmaxf(v, __shfl_xor(v, 1, 8));
        v = fmaxf(v, __shfl_xor(v, 2, 8));
        v = fmaxf(v, __shfl_xor(v, 4, 8));
        if (k == (o & 7)) so[o][nl] = v;
    }
    __syncthreads();
    {
        int o = tid >> 2;
        int s = tid & 3;
#pragma unroll
        for (int h = 0; h < 2; ++h) {
            int col = (s + 4 * h) << 2;
            float4 v = make_float4(so[o][col], so[o][col + 1], so[o][col + 2], so[o][col + 3]);
            *(float4*)(out + ((size_t)(b * M2 + o)) * NP + n0 + col) = v;
        }
    }
}

// ---------------------------------------------------------------------------
extern "C" void kernel_launch(void* const* d_in, const int* in_sizes, int n_in,
                              void* d_out, int out_size, void* d_ws, size_t ws_size,
                              hipStream_t stream)
{
    const float* xyz    = (const float*)d_in[0];
    const float* points = (const float*)d_in[1];
    const float* W0     = (const float*)d_in[2];
    const float* W1     = (const float*)d_in[3];
    const float* W2     = (const float*)d_in[4];
    float* out = (float*)d_out;

    char* ws = (char*)d_ws;
    float4* pts4 = (float4*)ws;                                  // 512 KB
    float*  feat = (float*)(ws + 524288);                        // 4 MB
    int*    idx  = (int*)(ws + 524288 + 4194304);                // 2 MB

    prep_kernel<<<BB * NP * 4 / 256, 256,  0, stream>>>(xyz, points, W0, pts4, feat);
    knn_kernel <<<BB * NP / 64,      1024, 0, stream>>>(pts4, idx);
    conv_kernel<<<BB * NP / 32,      256,  0, stream>>>(pts4, feat, idx, W0, W1, W2, out);
}